// Round 5
// baseline (166.559 us; speedup 1.0000x reference)
//
#include <hip/hip_runtime.h>
#include <math.h>

#define N 4096
#define D 768
#define MARGIN 1.0f
#define NTILE 1056   // sum over bi=0..31 of (64 - 2*bi) 128x64 tiles
#define NKT 24       // K-steps of BK=32
#define NSLOT 64     // scratch slots per row

typedef _Float16 half8 __attribute__((ext_vector_type(8)));
typedef _Float16 half4 __attribute__((ext_vector_type(4)));
typedef float f32x4 __attribute__((ext_vector_type(4)));

#define LD8(p, off) (*(const half8*)((p) + (off)))

// ---------------- Kernel 1: row L2-normalize (wave-per-row) + init ----------
__global__ __launch_bounds__(256) void normalize_kernel(const float* __restrict__ x,
                                                        _Float16* __restrict__ e,
                                                        float* __restrict__ sq,
                                                        float* __restrict__ ap_part,
                                                        float* __restrict__ an_part,
                                                        float* __restrict__ acc,
                                                        unsigned* __restrict__ counter) {
    const int tid = threadIdx.x;
    const int wave = tid >> 6, lane = tid & 63;
    const int row = blockIdx.x * 4 + wave;

    const float4* xr = (const float4*)(x + (size_t)row * D);   // 192 float4/row
    float4 f0 = xr[lane];
    float4 f1 = xr[lane + 64];
    float4 f2 = xr[lane + 128];

    float s = f0.x*f0.x + f0.y*f0.y + f0.z*f0.z + f0.w*f0.w
            + f1.x*f1.x + f1.y*f1.y + f1.z*f1.z + f1.w*f1.w
            + f2.x*f2.x + f2.y*f2.y + f2.z*f2.z + f2.w*f2.w;
    #pragma unroll
    for (int off = 1; off < 64; off <<= 1) s += __shfl_xor(s, off, 64);

    float scale = 1.0f / fmaxf(sqrtf(s), 1e-12f);

    half4* er = (half4*)(e + (size_t)row * D);
    half4 h0 = { (_Float16)(f0.x*scale), (_Float16)(f0.y*scale), (_Float16)(f0.z*scale), (_Float16)(f0.w*scale) };
    half4 h1 = { (_Float16)(f1.x*scale), (_Float16)(f1.y*scale), (_Float16)(f1.z*scale), (_Float16)(f1.w*scale) };
    half4 h2 = { (_Float16)(f2.x*scale), (_Float16)(f2.y*scale), (_Float16)(f2.z*scale), (_Float16)(f2.w*scale) };
    er[lane]       = h0;
    er[lane + 64]  = h1;
    er[lane + 128] = h2;

    if (lane == 0) sq[row] = s * scale * scale;

    // scratch init: 1024 blocks x 256 threads = 262144 = NSLOT*N exactly
    int g = blockIdx.x * 256 + tid;
    ap_part[g] = 0.0f;          // max identity (distances >= 0)
    an_part[g] = INFINITY;      // min identity

    if (blockIdx.x == 0 && tid == 0) { acc[0] = 0.f; acc[1] = 0.f; *counter = 0u; }
}

// ------- Kernel 2: MFMA Gram + mining, 128x64 tiles, barrier-free ----------
// No LDS in the K-loop: fragments load global->VGPR directly (e is L2/L3
// resident), register double-buffered 2 steps ahead. 16 independent waves/CU.
__global__ __launch_bounds__(256, 4) void mine_kernel(const _Float16* __restrict__ e,
                                                      const float* __restrict__ sq,
                                                      const int* __restrict__ labels,
                                                      float* __restrict__ ap_part,
                                                      float* __restrict__ an_part) {
    __shared__ float F[4 * 128];   // j-side cross-wave merge only (2KB)

    const int tid  = threadIdx.x;
    const int w    = tid >> 6;           // 0..3
    const int lane = tid & 63;
    const int ln15 = lane & 15;
    const int lq   = lane >> 4;          // 0..3
    const int wi   = w * 32;             // 1x4 wave grid: wave owns 32 unique rows

    // XCD-aware bijective swizzle (1056 = 8*132)
    const int b = (blockIdx.x & 7) * 132 + (blockIdx.x >> 3);

    // tile decode: row-panel bi (128 rows), col-panel cj (64 cols), cj >= 2*bi
    int bi = 0, rem = b;
    while (rem >= 64 - 2 * bi) { rem -= 64 - 2 * bi; ++bi; }
    const int cj = 2 * bi + rem;
    const bool diag = (rem <= 1);        // half-diagonal tiles: skip j-side
    const int i0 = bi * 128, j0 = cj * 64;

    // fragment stream base pointers (byte pointers; K advances 64B/step,
    // folds into the load offset immediate under full unroll)
    const char* a0 = (const char*)(e + (size_t)(i0 + wi + ln15) * D) + lq * 16;
    const char* a1 = a0 + 16 * (D * 2);
    const char* b0 = (const char*)(e + (size_t)(j0 + ln15) * D) + lq * 16;
    const char* b1 = b0 + 16 * (D * 2);
    const char* b2 = b0 + 32 * (D * 2);
    const char* b3 = b0 + 48 * (D * 2);

    f32x4 acc[2][4] = {};
    half8 fa[2][2], fb[2][4];

    // prologue: prefetch steps 0 and 1 into the two register sets
    fa[0][0] = LD8(a0, 0);  fa[0][1] = LD8(a1, 0);
    fb[0][0] = LD8(b0, 0);  fb[0][1] = LD8(b1, 0);
    fb[0][2] = LD8(b2, 0);  fb[0][3] = LD8(b3, 0);
    fa[1][0] = LD8(a0, 64); fa[1][1] = LD8(a1, 64);
    fb[1][0] = LD8(b0, 64); fb[1][1] = LD8(b1, 64);
    fb[1][2] = LD8(b2, 64); fb[1][3] = LD8(b3, 64);

    #pragma unroll
    for (int kt = 0; kt < NKT; ++kt) {
        const int cs = kt & 1;
        #pragma unroll
        for (int mt = 0; mt < 2; ++mt)
            #pragma unroll
            for (int nt = 0; nt < 4; ++nt)
                acc[mt][nt] = __builtin_amdgcn_mfma_f32_16x16x32_f16(fa[cs][mt], fb[cs][nt], acc[mt][nt], 0, 0, 0);
        if (kt + 2 < NKT) {   // refill the set just consumed (2 steps ahead)
            const int off = (kt + 2) * 64;
            fa[cs][0] = LD8(a0, off); fa[cs][1] = LD8(a1, off);
            fb[cs][0] = LD8(b0, off); fb[cs][1] = LD8(b1, off);
            fb[cs][2] = LD8(b2, off); fb[cs][3] = LD8(b3, off);
        }
    }

    // ---------------- epilogue: dist + dual-sided batch-hard mining ----------
    float sqi[2][4]; int labi[2][4];
    #pragma unroll
    for (int mt = 0; mt < 2; ++mt)
        #pragma unroll
        for (int rg = 0; rg < 4; ++rg) {
            int i = i0 + wi + mt * 16 + lq * 4 + rg;
            sqi[mt][rg] = sq[i];
            labi[mt][rg] = labels[i];
        }
    float sqj[4]; int labj[4];
    #pragma unroll
    for (int nt = 0; nt < 4; ++nt) {
        int j = j0 + nt * 16 + ln15;
        sqj[nt] = sq[j];
        labj[nt] = labels[j];
    }

    float api[2][4], ani[2][4], apj[4], anj[4];
    #pragma unroll
    for (int mt = 0; mt < 2; ++mt)
        #pragma unroll
        for (int rg = 0; rg < 4; ++rg) { api[mt][rg] = -INFINITY; ani[mt][rg] = INFINITY; }
    #pragma unroll
    for (int nt = 0; nt < 4; ++nt) { apj[nt] = -INFINITY; anj[nt] = INFINITY; }

    #pragma unroll
    for (int nt = 0; nt < 4; ++nt) {
        int j = j0 + nt * 16 + ln15;
        #pragma unroll
        for (int mt = 0; mt < 2; ++mt)
            #pragma unroll
            for (int rg = 0; rg < 4; ++rg) {
                int i = i0 + wi + mt * 16 + lq * 4 + rg;
                float d2 = sqi[mt][rg] + sqj[nt] - 2.0f * acc[mt][nt][rg];
                float dist = sqrtf(fmaxf(d2, 0.0f) + 1e-12f);
                if (labi[mt][rg] == labj[nt]) {
                    if (i != j) {
                        api[mt][rg] = fmaxf(api[mt][rg], dist);
                        apj[nt]     = fmaxf(apj[nt], dist);
                    }
                } else {
                    ani[mt][rg] = fminf(ani[mt][rg], dist);
                    anj[nt]     = fminf(anj[nt], dist);
                }
            }
    }

    // i-side: rows are unique per wave -> reduce over the 16 ln15-lanes and
    // store directly (no cross-wave merge, no atomics)
    #pragma unroll
    for (int mt = 0; mt < 2; ++mt)
        #pragma unroll
        for (int rg = 0; rg < 4; ++rg) {
            float a_ = api[mt][rg], n_ = ani[mt][rg];
            #pragma unroll
            for (int off = 1; off < 16; off <<= 1) {
                a_ = fmaxf(a_, __shfl_xor(a_, off, 64));
                n_ = fminf(n_, __shfl_xor(n_, off, 64));
            }
            if (ln15 == 0) {
                int row = i0 + wi + mt * 16 + lq * 4 + rg;
                ap_part[(size_t)cj * N + row] = a_;   // slot_i = cj (0..63)
                an_part[(size_t)cj * N + row] = n_;
            }
        }

    // j-side (skip on half-diagonal tiles — i-side coverage is complete)
    if (!diag) {
        #pragma unroll
        for (int nt = 0; nt < 4; ++nt) {
            float a_ = apj[nt], n_ = anj[nt];
            #pragma unroll
            for (int off = 16; off < 64; off <<= 1) {
                a_ = fmaxf(a_, __shfl_xor(a_, off, 64));
                n_ = fminf(n_, __shfl_xor(n_, off, 64));
            }
            if (lq == 0) {
                int jl = nt * 16 + ln15;                 // 0..63
                F[w * 128 + jl * 2]     = a_;
                F[w * 128 + jl * 2 + 1] = n_;
            }
        }
        __syncthreads();
        if (tid < 64) {   // merge the 4 waves (each covered different rows)
            float a_ = fmaxf(fmaxf(F[0 * 128 + tid * 2],     F[1 * 128 + tid * 2]),
                             fmaxf(F[2 * 128 + tid * 2],     F[3 * 128 + tid * 2]));
            float n_ = fminf(fminf(F[0 * 128 + tid * 2 + 1], F[1 * 128 + tid * 2 + 1]),
                             fminf(F[2 * 128 + tid * 2 + 1], F[3 * 128 + tid * 2 + 1]));
            int col = j0 + tid;
            ap_part[(size_t)bi * N + col] = a_;   // slot_j = bi (0..31); disjoint from i-side
            an_part[(size_t)bi * N + col] = n_;
        }
    }
}

// ------- Kernel 3: fold 64 scratch slots, compute loss ---------------------
__global__ __launch_bounds__(256) void reduce_kernel(const float* __restrict__ ap_part,
                                                     const float* __restrict__ an_part,
                                                     const int* __restrict__ labels,
                                                     float* __restrict__ acc,
                                                     unsigned* __restrict__ counter,
                                                     float* __restrict__ out) {
    const int tid = threadIdx.x;
    const int rl  = tid & 63;             // row within this block's 64-row strip
    const int q   = tid >> 6;             // wave id: covers slots [q*16, q*16+16)
    const int r   = blockIdx.x * 64 + rl; // 64 blocks x 64 rows

    __shared__ int cnt[4];
    __shared__ float Fa[4][64], Fn[4][64];
    if (tid < 4) cnt[tid] = 0;
    __syncthreads();
    int local[4] = {0, 0, 0, 0};
    for (int i = tid; i < N; i += 256) local[labels[i] & 3]++;
    #pragma unroll
    for (int c = 0; c < 4; c++) if (local[c]) atomicAdd(&cnt[c], local[c]);

    float ap = 0.0f, an = INFINITY;
    #pragma unroll
    for (int s = 0; s < 16; ++s) {
        int slot = q * 16 + s;
        ap = fmaxf(ap, ap_part[(size_t)slot * N + r]);
        an = fminf(an, an_part[(size_t)slot * N + r]);
    }
    Fa[q][rl] = ap; Fn[q][rl] = an;
    __syncthreads();

    if (tid < 64) {
        float a_ = fmaxf(fmaxf(Fa[0][tid], Fa[1][tid]), fmaxf(Fa[2][tid], Fa[3][tid]));
        float n_ = fminf(fminf(Fn[0][tid], Fn[1][tid]), fminf(Fn[2][tid], Fn[3][tid]));
        int row = blockIdx.x * 64 + tid;
        int l = labels[row] & 3;
        float sum = 0.f, nv = 0.f;
        if (cnt[l] >= 2) {
            nv = 1.f;
            if (n_ < 3.0e38f) sum = fmaxf(a_ - n_ + MARGIN, 0.f);
        }
        #pragma unroll
        for (int off = 32; off; off >>= 1) {
            sum += __shfl_down(sum, off, 64);
            nv  += __shfl_down(nv,  off, 64);
        }
        if (tid == 0) {
            atomicAdd(&acc[0], sum);
            atomicAdd(&acc[1], nv);
            __threadfence();
            if (atomicAdd(counter, 1u) == 63u) {
                float s_ = atomicAdd(&acc[0], 0.f);   // atomic read: coherent
                float nn = atomicAdd(&acc[1], 0.f);
                out[0] = s_ / fmaxf(nn, 1.f);
            }
        }
    }
}

// ---------------- Launch ----------------
extern "C" void kernel_launch(void* const* d_in, const int* in_sizes, int n_in,
                              void* d_out, int out_size, void* d_ws, size_t ws_size,
                              hipStream_t stream) {
    const float* x = (const float*)d_in[0];
    const int* labels = (const int*)d_in[1];
    float* out = (float*)d_out;

    _Float16* e = (_Float16*)d_ws;
    float* sq = (float*)(e + (size_t)N * D);
    float* ap_part = sq + N;                         // NSLOT*N floats (1MB)
    float* an_part = ap_part + (size_t)NSLOT * N;    // NSLOT*N floats (1MB)
    float* acc = an_part + (size_t)NSLOT * N;        // 2 floats
    unsigned* counter = (unsigned*)(acc + 2);

    normalize_kernel<<<N / 4, 256, 0, stream>>>(x, e, sq, ap_part, an_part, acc, counter);
    mine_kernel<<<NTILE, 256, 0, stream>>>(e, sq, labels, ap_part, an_part);
    reduce_kernel<<<N / 64, 256, 0, stream>>>(ap_part, an_part, labels, acc, counter, out);
}

// Round 6
// 116.174 us; speedup vs baseline: 1.4337x; 1.4337x over previous
//
#include <hip/hip_runtime.h>
#include <math.h>

#define N 4096
#define D 768
#define MARGIN 1.0f
#define NTILE 1056   // sum over bi=0..31 of (64 - 2*bi) 128x64 tiles
#define NKT 24       // K-steps of BK=32
#define NSLOT 64     // scratch slots per row

typedef _Float16 half8 __attribute__((ext_vector_type(8)));
typedef _Float16 half4 __attribute__((ext_vector_type(4)));
typedef float f32x4 __attribute__((ext_vector_type(4)));

__device__ __forceinline__ void gl2lds16(const void* g, void* l) {
    __builtin_amdgcn_global_load_lds((const __attribute__((address_space(1))) void*)g,
                                     (__attribute__((address_space(3))) void*)l, 16, 0, 0);
}

// counted vmcnt wait (literal must be compile-time)
template<int Nv>
__device__ __forceinline__ void wait_vm() {
    if constexpr (Nv == 0)      asm volatile("s_waitcnt vmcnt(0)" ::: "memory");
    else if constexpr (Nv == 1) asm volatile("s_waitcnt vmcnt(1)" ::: "memory");
    else                        asm volatile("s_waitcnt vmcnt(2)" ::: "memory");
}

// ---------------- Kernel 1: row L2-normalize (wave-per-row) + init ----------
__global__ __launch_bounds__(256) void normalize_kernel(const float* __restrict__ x,
                                                        _Float16* __restrict__ e,
                                                        float* __restrict__ sq,
                                                        float* __restrict__ ap_part,
                                                        float* __restrict__ an_part,
                                                        float* __restrict__ acc,
                                                        unsigned* __restrict__ counter) {
    const int tid = threadIdx.x;
    const int wave = tid >> 6, lane = tid & 63;
    const int row = blockIdx.x * 4 + wave;

    const float4* xr = (const float4*)(x + (size_t)row * D);   // 192 float4/row
    float4 f0 = xr[lane];
    float4 f1 = xr[lane + 64];
    float4 f2 = xr[lane + 128];

    float s = f0.x*f0.x + f0.y*f0.y + f0.z*f0.z + f0.w*f0.w
            + f1.x*f1.x + f1.y*f1.y + f1.z*f1.z + f1.w*f1.w
            + f2.x*f2.x + f2.y*f2.y + f2.z*f2.z + f2.w*f2.w;
    #pragma unroll
    for (int off = 1; off < 64; off <<= 1) s += __shfl_xor(s, off, 64);

    float scale = 1.0f / fmaxf(sqrtf(s), 1e-12f);

    half4* er = (half4*)(e + (size_t)row * D);
    half4 h0 = { (_Float16)(f0.x*scale), (_Float16)(f0.y*scale), (_Float16)(f0.z*scale), (_Float16)(f0.w*scale) };
    half4 h1 = { (_Float16)(f1.x*scale), (_Float16)(f1.y*scale), (_Float16)(f1.z*scale), (_Float16)(f1.w*scale) };
    half4 h2 = { (_Float16)(f2.x*scale), (_Float16)(f2.y*scale), (_Float16)(f2.z*scale), (_Float16)(f2.w*scale) };
    er[lane]       = h0;
    er[lane + 64]  = h1;
    er[lane + 128] = h2;

    if (lane == 0) sq[row] = s * scale * scale;

    // scratch init: 1024 blocks x 256 threads = 262144 = NSLOT*N exactly
    int g = blockIdx.x * 256 + tid;
    ap_part[g] = 0.0f;          // max identity (distances >= 0)
    an_part[g] = INFINITY;      // min identity

    if (blockIdx.x == 0 && tid == 0) { acc[0] = 0.f; acc[1] = 0.f; *counter = 0u; }
}

// ---------------- staging: one K-step (BK=32) of A(128)+B(64) rows ---------
// 512 threads: A = 512 granules (1/thread); B = 256 granules (waves 0-3 only,
// tid<256). Per-wave loads/stage: waves 0-3 -> 2, waves 4-7 -> 1 (uniform
// within each wave, so counted vmcnt works per wave).
__device__ __forceinline__ void stage_tile(const _Float16* __restrict__ e,
                                           int i0, int j0, int k0,
                                           unsigned short* Sb, int tid, int w) {
    {
        int r  = tid >> 2;
        int kg = (tid & 3) ^ ((r >> 1) & 3);
        gl2lds16(e + (size_t)(i0 + r) * D + k0 + kg * 8,
                 (char*)Sb + tid * 16);
    }
    if (w < 4) {   // tid < 256
        int r  = tid >> 2;
        int kg = (tid & 3) ^ ((r >> 1) & 3);
        gl2lds16(e + (size_t)(j0 + r) * D + k0 + kg * 8,
                 (char*)Sb + 8192 + tid * 16);
    }
}

// ------- Kernel 2: MFMA Gram + mining, 128x64 tiles, 8 waves @ <=64 VGPR ---
// LDS per buffer: A 128x32 halves (8KB, XOR-swizzled) | B 64x32 (4KB) = 12KB.
// 3 buffers = 36KB; launch_bounds(512,8) -> <=64 VGPR -> 4 blocks/CU
// = 32 waves/CU (2x the r3 TLP).
__global__ __launch_bounds__(512, 8) void mine_kernel(const _Float16* __restrict__ e,
                                                      const float* __restrict__ sq,
                                                      const int* __restrict__ labels,
                                                      float* __restrict__ ap_part,
                                                      float* __restrict__ an_part) {
    __shared__ unsigned short S[3 * 6144];   // 36KB

    const int tid  = threadIdx.x;
    const int w    = tid >> 6;           // 0..7
    const int lane = tid & 63;
    const int ln15 = lane & 15;
    const int lq   = lane >> 4;          // 0..3
    const int wr   = w >> 1, wc = w & 1; // 4x2 wave grid, wave-tile 32x32
    const int wi   = wr * 32, wjL = wc * 32;

    // XCD-aware bijective swizzle (1056 = 8*132)
    const int b = (blockIdx.x & 7) * 132 + (blockIdx.x >> 3);

    // tile decode: row-panel bi (128 rows), col-panel cj (64 cols), cj >= 2*bi
    int bi = 0, rem = b;
    while (rem >= 64 - 2 * bi) { rem -= 64 - 2 * bi; ++bi; }
    const int cj = 2 * bi + rem;
    const bool diag = (rem <= 1);        // half-diagonal tiles: skip j-side
    const int i0 = bi * 128, j0 = cj * 64;

    f32x4 acc[2][2] = {};

    // prologue: stage steps 0 and 1 (depth-2 in flight)
    stage_tile(e, i0, j0, 0,  S,        tid, w);
    stage_tile(e, i0, j0, 32, S + 6144, tid, w);

    int cur = 0, nx2 = 2;
    for (int kt = 0; kt < NKT; ++kt) {
        // retire step-kt's stage only (stage kt+1 stays in flight)
        if (kt < NKT - 1) { if (w < 4) wait_vm<2>(); else wait_vm<1>(); }
        else              wait_vm<0>();
        __builtin_amdgcn_s_barrier();
        __builtin_amdgcn_sched_barrier(0);

        // issue step kt+2 into the buffer last read at iter kt-1 (all waves
        // are past barrier kt, so those ds_reads completed)
        if (kt + 2 < NKT)
            stage_tile(e, i0, j0, (kt + 2) * 32, S + nx2 * 6144, tid, w);
        __builtin_amdgcn_sched_barrier(0);

        const unsigned short* Sb = S + cur * 6144;
        half8 af[2], bf[2];
        #pragma unroll
        for (int mt = 0; mt < 2; ++mt) {
            int r  = wi + mt * 16 + ln15;
            int kx = lq ^ ((r >> 1) & 3);
            af[mt] = *(const half8*)&Sb[r * 32 + kx * 8];
        }
        #pragma unroll
        for (int nt = 0; nt < 2; ++nt) {
            int c  = wjL + nt * 16 + ln15;
            int kx = lq ^ ((c >> 1) & 3);
            bf[nt] = *(const half8*)&Sb[4096 + c * 32 + kx * 8];
        }
        __builtin_amdgcn_s_setprio(1);
        #pragma unroll
        for (int mt = 0; mt < 2; ++mt)
            #pragma unroll
            for (int nt = 0; nt < 2; ++nt)
                acc[mt][nt] = __builtin_amdgcn_mfma_f32_16x16x32_f16(af[mt], bf[nt], acc[mt][nt], 0, 0, 0);
        __builtin_amdgcn_s_setprio(0);

        cur = (cur == 2) ? 0 : cur + 1;
        nx2 = (nx2 == 2) ? 0 : nx2 + 1;
    }

    // ---------------- epilogue: dist + dual-sided batch-hard mining ----------
    float sqi[2][4]; int labi[2][4];
    #pragma unroll
    for (int mt = 0; mt < 2; ++mt)
        #pragma unroll
        for (int rg = 0; rg < 4; ++rg) {
            int i = i0 + wi + mt * 16 + lq * 4 + rg;
            sqi[mt][rg] = sq[i];
            labi[mt][rg] = labels[i];
        }
    float sqj[2]; int labj[2];
    #pragma unroll
    for (int nt = 0; nt < 2; ++nt) {
        int j = j0 + wjL + nt * 16 + ln15;
        sqj[nt] = sq[j];
        labj[nt] = labels[j];
    }

    float api[2][4], ani[2][4], apj[2], anj[2];
    #pragma unroll
    for (int mt = 0; mt < 2; ++mt)
        #pragma unroll
        for (int rg = 0; rg < 4; ++rg) { api[mt][rg] = -INFINITY; ani[mt][rg] = INFINITY; }
    #pragma unroll
    for (int nt = 0; nt < 2; ++nt) { apj[nt] = -INFINITY; anj[nt] = INFINITY; }

    #pragma unroll
    for (int nt = 0; nt < 2; ++nt) {
        int j = j0 + wjL + nt * 16 + ln15;
        #pragma unroll
        for (int mt = 0; mt < 2; ++mt)
            #pragma unroll
            for (int rg = 0; rg < 4; ++rg) {
                int i = i0 + wi + mt * 16 + lq * 4 + rg;
                float d2 = sqi[mt][rg] + sqj[nt] - 2.0f * acc[mt][nt][rg];
                float dist = sqrtf(fmaxf(d2, 0.0f) + 1e-12f);
                if (labi[mt][rg] == labj[nt]) {
                    if (i != j) {
                        api[mt][rg] = fmaxf(api[mt][rg], dist);
                        apj[nt]     = fmaxf(apj[nt], dist);
                    }
                } else {
                    ani[mt][rg] = fminf(ani[mt][rg], dist);
                    anj[nt]     = fminf(anj[nt], dist);
                }
            }
    }

    // ---- atomic-free outputs: LDS wave-merge, one plain store per (row,slot)
    // F overlays buffer 0: its last read was step 21; all waves are past
    // barrier 23 before any wave reaches the epilogue -> safe.
    float* F = (float*)S;   // 8 waves x 32 entries x 2 floats = 2KB

    // i-side: reduce over the 16 ln15-lanes, stage to LDS
    #pragma unroll
    for (int mt = 0; mt < 2; ++mt)
        #pragma unroll
        for (int rg = 0; rg < 4; ++rg) {
            float a_ = api[mt][rg], n_ = ani[mt][rg];
            #pragma unroll
            for (int off = 1; off < 16; off <<= 1) {
                a_ = fmaxf(a_, __shfl_xor(a_, off, 64));
                n_ = fminf(n_, __shfl_xor(n_, off, 64));
            }
            if (ln15 == 0) {
                int rl = mt * 16 + lq * 4 + rg;          // 0..31
                F[w * 64 + rl * 2]     = a_;
                F[w * 64 + rl * 2 + 1] = n_;
            }
        }
    __syncthreads();
    if (tid < 128) {   // 128 rows; merge the 2 waves {2wr2, 2wr2+1} per band
        int wr2 = tid >> 5, rl = tid & 31;
        float a_ = fmaxf(F[(2 * wr2) * 64 + rl * 2],     F[(2 * wr2 + 1) * 64 + rl * 2]);
        float n_ = fminf(F[(2 * wr2) * 64 + rl * 2 + 1], F[(2 * wr2 + 1) * 64 + rl * 2 + 1]);
        int row = i0 + wr2 * 32 + rl;
        ap_part[(size_t)cj * N + row] = a_;   // slot_i = cj (0..63)
        an_part[(size_t)cj * N + row] = n_;
    }

    // j-side (skip on half-diagonal tiles — i-side coverage is complete)
    if (!diag) {
        __syncthreads();
        #pragma unroll
        for (int nt = 0; nt < 2; ++nt) {
            float a_ = apj[nt], n_ = anj[nt];
            #pragma unroll
            for (int off = 16; off < 64; off <<= 1) {
                a_ = fmaxf(a_, __shfl_xor(a_, off, 64));
                n_ = fminf(n_, __shfl_xor(n_, off, 64));
            }
            if (lq == 0) {
                int jl = nt * 16 + ln15;                 // 0..31
                F[w * 64 + jl * 2]     = a_;
                F[w * 64 + jl * 2 + 1] = n_;
            }
        }
        __syncthreads();
        if (tid < 64) {   // 64 cols; merge the 4 waves {wc2, wc2+2, wc2+4, wc2+6}
            int wc2 = tid >> 5, jl = tid & 31;
            float a_ = fmaxf(fmaxf(F[(wc2 + 0) * 64 + jl * 2], F[(wc2 + 2) * 64 + jl * 2]),
                             fmaxf(F[(wc2 + 4) * 64 + jl * 2], F[(wc2 + 6) * 64 + jl * 2]));
            float n_ = fminf(fminf(F[(wc2 + 0) * 64 + jl * 2 + 1], F[(wc2 + 2) * 64 + jl * 2 + 1]),
                             fminf(F[(wc2 + 4) * 64 + jl * 2 + 1], F[(wc2 + 6) * 64 + jl * 2 + 1]));
            int col = j0 + wc2 * 32 + jl;
            ap_part[(size_t)bi * N + col] = a_;   // slot_j = bi (0..31); disjoint from i-side
            an_part[(size_t)bi * N + col] = n_;
        }
    }
}

// ------- Kernel 3: fold 64 scratch slots, compute loss ---------------------
__global__ __launch_bounds__(256) void reduce_kernel(const float* __restrict__ ap_part,
                                                     const float* __restrict__ an_part,
                                                     const int* __restrict__ labels,
                                                     float* __restrict__ acc,
                                                     unsigned* __restrict__ counter,
                                                     float* __restrict__ out) {
    const int tid = threadIdx.x;
    const int rl  = tid & 63;             // row within this block's 64-row strip
    const int q   = tid >> 6;             // wave id: covers slots [q*16, q*16+16)
    const int r   = blockIdx.x * 64 + rl; // 64 blocks x 64 rows

    __shared__ int cnt[4];
    __shared__ float Fa[4][64], Fn[4][64];
    if (tid < 4) cnt[tid] = 0;
    __syncthreads();
    int local[4] = {0, 0, 0, 0};
    for (int i = tid; i < N; i += 256) local[labels[i] & 3]++;
    #pragma unroll
    for (int c = 0; c < 4; c++) if (local[c]) atomicAdd(&cnt[c], local[c]);

    float ap = 0.0f, an = INFINITY;
    #pragma unroll
    for (int s = 0; s < 16; ++s) {
        int slot = q * 16 + s;
        ap = fmaxf(ap, ap_part[(size_t)slot * N + r]);
        an = fminf(an, an_part[(size_t)slot * N + r]);
    }
    Fa[q][rl] = ap; Fn[q][rl] = an;
    __syncthreads();

    if (tid < 64) {
        float a_ = fmaxf(fmaxf(Fa[0][tid], Fa[1][tid]), fmaxf(Fa[2][tid], Fa[3][tid]));
        float n_ = fminf(fminf(Fn[0][tid], Fn[1][tid]), fminf(Fn[2][tid], Fn[3][tid]));
        int row = blockIdx.x * 64 + tid;
        int l = labels[row] & 3;
        float sum = 0.f, nv = 0.f;
        if (cnt[l] >= 2) {
            nv = 1.f;
            if (n_ < 3.0e38f) sum = fmaxf(a_ - n_ + MARGIN, 0.f);
        }
        #pragma unroll
        for (int off = 32; off; off >>= 1) {
            sum += __shfl_down(sum, off, 64);
            nv  += __shfl_down(nv,  off, 64);
        }
        if (tid == 0) {
            atomicAdd(&acc[0], sum);
            atomicAdd(&acc[1], nv);
            __threadfence();
            if (atomicAdd(counter, 1u) == 63u) {
                float s_ = atomicAdd(&acc[0], 0.f);   // atomic read: coherent
                float nn = atomicAdd(&acc[1], 0.f);
                out[0] = s_ / fmaxf(nn, 1.f);
            }
        }
    }
}

// ---------------- Launch ----------------
extern "C" void kernel_launch(void* const* d_in, const int* in_sizes, int n_in,
                              void* d_out, int out_size, void* d_ws, size_t ws_size,
                              hipStream_t stream) {
    const float* x = (const float*)d_in[0];
    const int* labels = (const int*)d_in[1];
    float* out = (float*)d_out;

    _Float16* e = (_Float16*)d_ws;
    float* sq = (float*)(e + (size_t)N * D);
    float* ap_part = sq + N;                         // NSLOT*N floats (1MB)
    float* an_part = ap_part + (size_t)NSLOT * N;    // NSLOT*N floats (1MB)
    float* acc = an_part + (size_t)NSLOT * N;        // 2 floats
    unsigned* counter = (unsigned*)(acc + 2);

    normalize_kernel<<<N / 4, 256, 0, stream>>>(x, e, sq, ap_part, an_part, acc, counter);
    mine_kernel<<<NTILE, 512, 0, stream>>>(e, sq, labels, ap_part, an_part);
    reduce_kernel<<<N / 64, 256, 0, stream>>>(ap_part, an_part, labels, acc, counter, out);
}